// Round 1
// baseline (31575.488 us; speedup 1.0000x reference)
//
#include <hip/hip_runtime.h>
#include <cstdint>
#include <cstddef>

#define N_ 64
#define T_ 512
#define D_ 1024
#define H_ 1024
#define FH 4096  // 4*H

static __device__ __forceinline__ float sigmoidf_(float x) {
  return 1.0f / (1.0f + __expf(-x));
}

static __device__ __forceinline__ uint16_t f2bf_(float f) {
  union { float f; uint32_t u; } v; v.f = f;
  uint32_t u = v.u + 0x7FFFu + ((v.u >> 16) & 1u);
  return (uint16_t)(u >> 16);
}
static __device__ __forceinline__ float bf2f_(uint16_t s) {
  union { uint32_t u; float f; } v; v.u = ((uint32_t)s) << 16;
  return v.f;
}
static __device__ __forceinline__ float ldxw_(const float* p) { return *p; }
static __device__ __forceinline__ float ldxw_(const uint16_t* p) { return bf2f_(*p); }

// ---------------------------------------------------------------------------
// Phase 1: xW = x @ Wx + b.   x:[32768,1024]  Wx:[1024,4096]  -> xw:[32768,4096]
// 128x128 block tile, BK=16, 256 threads, 8x8 per-thread tile. fp32 VALU GEMM.
// ---------------------------------------------------------------------------
template <typename ST>
__global__ __launch_bounds__(256) void gemm_xw_k(
    const float* __restrict__ x, const float* __restrict__ Wx,
    const float* __restrict__ bias, ST* __restrict__ xw) {
  __shared__ float As[16][128];  // transposed: As[k][m]
  __shared__ float Bs[16][128];  // Bs[k][n]
  const int tid = threadIdx.x;
  const int bn = blockIdx.x & 31;   // 4096/128 = 32 col tiles
  const int bm = blockIdx.x >> 5;   // 32768/128 = 256 row tiles
  const int m0 = bm << 7, n0 = bn << 7;
  const int ty = tid >> 4, tx = tid & 15;

  float acc[8][8];
#pragma unroll
  for (int i = 0; i < 8; ++i)
#pragma unroll
    for (int j = 0; j < 8; ++j) acc[i][j] = 0.0f;

  for (int k0 = 0; k0 < D_; k0 += 16) {
    __syncthreads();
    // stage A tile (transposed store)
#pragma unroll
    for (int p = 0; p < 2; ++p) {
      int idx = tid + (p << 8);
      int m = idx >> 2, kq = (idx & 3) << 2;
      float4 v = *reinterpret_cast<const float4*>(x + (size_t)(m0 + m) * D_ + k0 + kq);
      As[kq][m] = v.x; As[kq + 1][m] = v.y; As[kq + 2][m] = v.z; As[kq + 3][m] = v.w;
    }
    // stage B tile (straight copy)
#pragma unroll
    for (int p = 0; p < 2; ++p) {
      int idx = tid + (p << 8);
      int k = idx >> 5, c4 = (idx & 31) << 2;
      *reinterpret_cast<float4*>(&Bs[k][c4]) =
          *reinterpret_cast<const float4*>(Wx + (size_t)(k0 + k) * FH + n0 + c4);
    }
    __syncthreads();
#pragma unroll
    for (int k = 0; k < 16; ++k) {
      float4 a0 = *reinterpret_cast<const float4*>(&As[k][ty << 3]);
      float4 a1 = *reinterpret_cast<const float4*>(&As[k][(ty << 3) + 4]);
      float4 b0 = *reinterpret_cast<const float4*>(&Bs[k][tx << 3]);
      float4 b1 = *reinterpret_cast<const float4*>(&Bs[k][(tx << 3) + 4]);
      float av[8] = {a0.x, a0.y, a0.z, a0.w, a1.x, a1.y, a1.z, a1.w};
      float bv[8] = {b0.x, b0.y, b0.z, b0.w, b1.x, b1.y, b1.z, b1.w};
#pragma unroll
      for (int i = 0; i < 8; ++i)
#pragma unroll
        for (int j = 0; j < 8; ++j) acc[i][j] = fmaf(av[i], bv[j], acc[i][j]);
    }
  }

  float bv2[8];
#pragma unroll
  for (int j = 0; j < 8; ++j) bv2[j] = bias[n0 + (tx << 3) + j];

#pragma unroll
  for (int i = 0; i < 8; ++i) {
    size_t row = (size_t)(m0 + (ty << 3) + i) * FH + n0 + (tx << 3);
    if constexpr (sizeof(ST) == 4) {
      float4 o0, o1;
      o0.x = acc[i][0] + bv2[0]; o0.y = acc[i][1] + bv2[1];
      o0.z = acc[i][2] + bv2[2]; o0.w = acc[i][3] + bv2[3];
      o1.x = acc[i][4] + bv2[4]; o1.y = acc[i][5] + bv2[5];
      o1.z = acc[i][6] + bv2[6]; o1.w = acc[i][7] + bv2[7];
      *reinterpret_cast<float4*>((float*)xw + row) = o0;
      *reinterpret_cast<float4*>((float*)xw + row + 4) = o1;
    } else {
      ushort4 u0, u1;
      u0.x = f2bf_(acc[i][0] + bv2[0]); u0.y = f2bf_(acc[i][1] + bv2[1]);
      u0.z = f2bf_(acc[i][2] + bv2[2]); u0.w = f2bf_(acc[i][3] + bv2[3]);
      u1.x = f2bf_(acc[i][4] + bv2[4]); u1.y = f2bf_(acc[i][5] + bv2[5]);
      u1.z = f2bf_(acc[i][6] + bv2[6]); u1.w = f2bf_(acc[i][7] + bv2[7]);
      *reinterpret_cast<ushort4*>((uint16_t*)xw + row) = u0;
      *reinterpret_cast<ushort4*>((uint16_t*)xw + row + 4) = u1;
    }
  }
}

// ---------------------------------------------------------------------------
// Phase 2: one timestep. preact = xw_t + h_prev @ Wh (+ optionally x_t @ Wx + b
// in FUSED mode when no workspace for xw). Then gates -> h_t, c_t.
// Grid: 256 blocks x 256 thr. Block = (n-half: 32 rows) x (8 h-cols = 32 gate cols).
// K chunked by 128 through LDS; 2x2 per-thread tile (broadcast-heavy LDS reads).
// ---------------------------------------------------------------------------
template <typename XT, bool FUSED>
__global__ __launch_bounds__(256) void lstm_step_k(
    const XT* __restrict__ xw,      // !FUSED: xw base [N*T][4096]; FUSED: x + t*D
    const float* __restrict__ Wx,   // FUSED only
    const float* __restrict__ Wh,   // [1024][4096]
    const float* __restrict__ bias, // FUSED only
    const float* __restrict__ h_prev, long long hstride,
    float* __restrict__ cbuf,       // [64][1024]
    float* __restrict__ h_out,      // d_out + t*H; row stride T*H
    int t, int first) {
  __shared__ float hS[32][128];
  __shared__ float wT[32][132];  // [local gate col][k], padded
  __shared__ float pre[32][34];
  const int tid = threadIdx.x;
  const int colblk = blockIdx.x & 127;
  const int nh = blockIdx.x >> 7;
  const int j0 = colblk << 3;  // h-col base (8 per block)
  const int n0 = nh << 5;      // batch-row base (32 per block)
  const int ng = tid >> 4, cg = tid & 15;
  const int na = ng << 1, ca = cg << 1;

  float acc[2][2] = {{0.f, 0.f}, {0.f, 0.f}};

#pragma unroll
  for (int pr = 0; pr < (FUSED ? 2 : 1); ++pr) {
    const float* src = (pr == 0) ? h_prev : (const float*)xw;
    long long sstr = (pr == 0) ? hstride : (long long)T_ * D_;
    const float* W = (pr == 0) ? Wh : Wx;
    for (int k0 = 0; k0 < 1024; k0 += 128) {
      __syncthreads();
      // stage h chunk [32][128]
#pragma unroll
      for (int p = 0; p < 4; ++p) {
        int idx = tid + (p << 8);
        int r = idx >> 5, c4 = (idx & 31) << 2;
        *reinterpret_cast<float4*>(&hS[r][c4]) =
            *reinterpret_cast<const float4*>(src + (size_t)(n0 + r) * sstr + k0 + c4);
      }
      // stage Wh chunk transposed: local col = g*8 + jj  <->  global g*1024 + j0 + jj
#pragma unroll
      for (int p = 0; p < 4; ++p) {
        int idx = tid + (p << 8);
        int k = idx >> 3, sub = idx & 7;
        int g = sub >> 1, hf = (sub & 1) << 2;
        float4 v = *reinterpret_cast<const float4*>(
            W + (size_t)(k0 + k) * FH + g * H_ + j0 + hf);
        int cb = (g << 3) + hf;
        wT[cb][k] = v.x; wT[cb + 1][k] = v.y; wT[cb + 2][k] = v.z; wT[cb + 3][k] = v.w;
      }
      __syncthreads();
#pragma unroll
      for (int kk = 0; kk < 128; kk += 4) {
        float4 h0 = *reinterpret_cast<const float4*>(&hS[na][kk]);
        float4 h1 = *reinterpret_cast<const float4*>(&hS[na + 1][kk]);
        float4 w0 = *reinterpret_cast<const float4*>(&wT[ca][kk]);
        float4 w1 = *reinterpret_cast<const float4*>(&wT[ca + 1][kk]);
        acc[0][0] = fmaf(h0.x, w0.x, acc[0][0]);
        acc[0][0] = fmaf(h0.y, w0.y, acc[0][0]);
        acc[0][0] = fmaf(h0.z, w0.z, acc[0][0]);
        acc[0][0] = fmaf(h0.w, w0.w, acc[0][0]);
        acc[0][1] = fmaf(h0.x, w1.x, acc[0][1]);
        acc[0][1] = fmaf(h0.y, w1.y, acc[0][1]);
        acc[0][1] = fmaf(h0.z, w1.z, acc[0][1]);
        acc[0][1] = fmaf(h0.w, w1.w, acc[0][1]);
        acc[1][0] = fmaf(h1.x, w0.x, acc[1][0]);
        acc[1][0] = fmaf(h1.y, w0.y, acc[1][0]);
        acc[1][0] = fmaf(h1.z, w0.z, acc[1][0]);
        acc[1][0] = fmaf(h1.w, w0.w, acc[1][0]);
        acc[1][1] = fmaf(h1.x, w1.x, acc[1][1]);
        acc[1][1] = fmaf(h1.y, w1.y, acc[1][1]);
        acc[1][1] = fmaf(h1.z, w1.z, acc[1][1]);
        acc[1][1] = fmaf(h1.w, w1.w, acc[1][1]);
      }
    }
  }

  // write partial preacts to LDS, then gate epilogue: thread <-> (n-local, j-local)
  pre[na][ca] = acc[0][0];
  pre[na][ca + 1] = acc[0][1];
  pre[na + 1][ca] = acc[1][0];
  pre[na + 1][ca + 1] = acc[1][1];
  __syncthreads();

  const int nl = tid >> 3, jl = tid & 7;
  const int n = n0 + nl;
  const int jg = j0 + jl;
  float ai = pre[nl][jl];
  float af = pre[nl][8 + jl];
  float ao = pre[nl][16 + jl];
  float ag = pre[nl][24 + jl];
  if constexpr (FUSED) {
    ai += bias[jg];
    af += bias[H_ + jg];
    ao += bias[2 * H_ + jg];
    ag += bias[3 * H_ + jg];
  } else {
    const XT* xr = xw + ((size_t)n * T_ + t) * FH;
    ai += ldxw_(xr + jg);
    af += ldxw_(xr + H_ + jg);
    ao += ldxw_(xr + 2 * H_ + jg);
    ag += ldxw_(xr + 3 * H_ + jg);
  }
  float cp = first ? 0.0f : cbuf[n * H_ + jg];
  float iv = sigmoidf_(ai);
  float fv = sigmoidf_(af);
  float ov = sigmoidf_(ao);
  float gv = tanhf(ag);
  float cn = fmaf(fv, cp, iv * gv);
  float hn = ov * tanhf(cn);
  cbuf[n * H_ + jg] = cn;
  h_out[(size_t)n * ((size_t)T_ * H_) + jg] = hn;
}

// ---------------------------------------------------------------------------
extern "C" void kernel_launch(void* const* d_in, const int* in_sizes, int n_in,
                              void* d_out, int out_size, void* d_ws, size_t ws_size,
                              hipStream_t stream) {
  (void)in_sizes; (void)n_in; (void)out_size;
  const float* x  = (const float*)d_in[0];
  const float* h0 = (const float*)d_in[1];
  const float* Wx = (const float*)d_in[2];
  const float* Wh = (const float*)d_in[3];
  const float* b  = (const float*)d_in[4];
  float* out = (float*)d_out;

  const size_t C_BYTES = (size_t)N_ * H_ * sizeof(float);      // 256 KB
  const size_t XW_ELEMS = (size_t)N_ * T_ * FH;                // 128M elems
  float* cbuf = (float*)d_ws;

  if (ws_size >= C_BYTES + XW_ELEMS * sizeof(float)) {
    // fp32 xW path (needs ~512.25 MB workspace)
    float* xwbuf = (float*)((char*)d_ws + C_BYTES);
    gemm_xw_k<float><<<dim3(8192), dim3(256), 0, stream>>>(x, Wx, b, xwbuf);
    for (int t = 0; t < T_; ++t) {
      const float* hp = (t == 0) ? h0 : out + (size_t)(t - 1) * H_;
      long long hstr = (t == 0) ? (long long)H_ : (long long)T_ * H_;
      lstm_step_k<float, false><<<dim3(256), dim3(256), 0, stream>>>(
          xwbuf, nullptr, Wh, nullptr, hp, hstr, cbuf, out + (size_t)t * H_, t, t == 0);
    }
  } else if (ws_size >= C_BYTES + XW_ELEMS * sizeof(uint16_t)) {
    // bf16 xW path (needs ~256.25 MB workspace)
    uint16_t* xwbuf = (uint16_t*)((char*)d_ws + C_BYTES);
    gemm_xw_k<uint16_t><<<dim3(8192), dim3(256), 0, stream>>>(x, Wx, b, xwbuf);
    for (int t = 0; t < T_; ++t) {
      const float* hp = (t == 0) ? h0 : out + (size_t)(t - 1) * H_;
      long long hstr = (t == 0) ? (long long)H_ : (long long)T_ * H_;
      lstm_step_k<uint16_t, false><<<dim3(256), dim3(256), 0, stream>>>(
          xwbuf, nullptr, Wh, nullptr, hp, hstr, cbuf, out + (size_t)t * H_, t, t == 0);
    }
  } else {
    // fully fused fallback: recompute x_t @ Wx inside each step (ws only for c)
    for (int t = 0; t < T_; ++t) {
      const float* hp = (t == 0) ? h0 : out + (size_t)(t - 1) * H_;
      long long hstr = (t == 0) ? (long long)H_ : (long long)T_ * H_;
      lstm_step_k<float, true><<<dim3(256), dim3(256), 0, stream>>>(
          x + (size_t)t * D_, Wx, Wh, b, hp, hstr, cbuf, out + (size_t)t * H_, t, t == 0);
    }
  }
}

// Round 4
// 12561.307 us; speedup vs baseline: 2.5137x; 2.5137x over previous
//
#include <hip/hip_runtime.h>
#include <cstdint>
#include <cstddef>

#define N_ 64
#define T_ 512
#define D_ 1024
#define H_ 1024
#define FH 4096  // 4*H

static __device__ __forceinline__ uint16_t f2bf_(float f) {
  union { float f; uint32_t u; } v; v.f = f;
  uint32_t u = v.u + 0x7FFFu + ((v.u >> 16) & 1u);
  return (uint16_t)(u >> 16);
}
static __device__ __forceinline__ float bf2f_(uint16_t s) {
  union { uint32_t u; float f; } v; v.u = ((uint32_t)s) << 16;
  return v.f;
}
static __device__ __forceinline__ float ldxw_(const float* p) { return *p; }
static __device__ __forceinline__ float ldxw_(const uint16_t* p) { return bf2f_(*p); }

// ---------------------------------------------------------------------------
// Repack W [1024][4096] -> Wt[bid 0..255][r 0..15][k 0..1023], r = gate*4+jj,
// block bid owns h-cols bid*4..bid*4+3. Writes coalesced (float4 over k).
// Exactly 256*16*256 = 1,048,576 float4 -> 4096 blocks x 256 threads.
// ---------------------------------------------------------------------------
__global__ __launch_bounds__(256) void repack_k(const float* __restrict__ W,
                                                float* __restrict__ Wt) {
  const int i = blockIdx.x * 256 + threadIdx.x;  // 1M float4 units
  const int k4 = i & 255, r = (i >> 8) & 15, bid = i >> 12;  // bid 0..255
  const int col = (r >> 2) * H_ + (bid << 2) + (r & 3);
  const size_t k = (size_t)(k4 << 2);
  float4 v;
  v.x = W[(k + 0) * FH + col];
  v.y = W[(k + 1) * FH + col];
  v.z = W[(k + 2) * FH + col];
  v.w = W[(k + 3) * FH + col];
  reinterpret_cast<float4*>(Wt)[i] = v;
}

// ---------------------------------------------------------------------------
// Phase 1: xW = x @ Wx + b.  [32768,1024]@[1024,4096]. fp32 VALU GEMM (proven).
// ---------------------------------------------------------------------------
template <typename ST>
__global__ __launch_bounds__(256) void gemm_xw_k(
    const float* __restrict__ x, const float* __restrict__ Wx,
    const float* __restrict__ bias, ST* __restrict__ xw) {
  __shared__ float As[16][128];
  __shared__ float Bs[16][128];
  const int tid = threadIdx.x;
  const int bn = blockIdx.x & 31;
  const int bm = blockIdx.x >> 5;
  const int m0 = bm << 7, n0 = bn << 7;
  const int ty = tid >> 4, tx = tid & 15;

  float acc[8][8];
#pragma unroll
  for (int i = 0; i < 8; ++i)
#pragma unroll
    for (int j = 0; j < 8; ++j) acc[i][j] = 0.0f;

  for (int k0 = 0; k0 < D_; k0 += 16) {
    __syncthreads();
#pragma unroll
    for (int p = 0; p < 2; ++p) {
      int idx = tid + (p << 8);
      int m = idx >> 2, kq = (idx & 3) << 2;
      float4 v = *reinterpret_cast<const float4*>(x + (size_t)(m0 + m) * D_ + k0 + kq);
      As[kq][m] = v.x; As[kq + 1][m] = v.y; As[kq + 2][m] = v.z; As[kq + 3][m] = v.w;
    }
#pragma unroll
    for (int p = 0; p < 2; ++p) {
      int idx = tid + (p << 8);
      int k = idx >> 5, c4 = (idx & 31) << 2;
      *reinterpret_cast<float4*>(&Bs[k][c4]) =
          *reinterpret_cast<const float4*>(Wx + (size_t)(k0 + k) * FH + n0 + c4);
    }
    __syncthreads();
#pragma unroll
    for (int k = 0; k < 16; ++k) {
      float4 a0 = *reinterpret_cast<const float4*>(&As[k][ty << 3]);
      float4 a1 = *reinterpret_cast<const float4*>(&As[k][(ty << 3) + 4]);
      float4 b0 = *reinterpret_cast<const float4*>(&Bs[k][tx << 3]);
      float4 b1 = *reinterpret_cast<const float4*>(&Bs[k][(tx << 3) + 4]);
      float av[8] = {a0.x, a0.y, a0.z, a0.w, a1.x, a1.y, a1.z, a1.w};
      float bv[8] = {b0.x, b0.y, b0.z, b0.w, b1.x, b1.y, b1.z, b1.w};
#pragma unroll
      for (int i = 0; i < 8; ++i)
#pragma unroll
        for (int j = 0; j < 8; ++j) acc[i][j] = fmaf(av[i], bv[j], acc[i][j]);
    }
  }

  float bv2[8];
#pragma unroll
  for (int j = 0; j < 8; ++j) bv2[j] = bias[n0 + (tx << 3) + j];

#pragma unroll
  for (int i = 0; i < 8; ++i) {
    size_t row = (size_t)(m0 + (ty << 3) + i) * FH + n0 + (tx << 3);
    if constexpr (sizeof(ST) == 4) {
      float4 o0, o1;
      o0.x = acc[i][0] + bv2[0]; o0.y = acc[i][1] + bv2[1];
      o0.z = acc[i][2] + bv2[2]; o0.w = acc[i][3] + bv2[3];
      o1.x = acc[i][4] + bv2[4]; o1.y = acc[i][5] + bv2[5];
      o1.z = acc[i][6] + bv2[6]; o1.w = acc[i][7] + bv2[7];
      *reinterpret_cast<float4*>((float*)xw + row) = o0;
      *reinterpret_cast<float4*>((float*)xw + row + 4) = o1;
    } else {
      ushort4 u0, u1;
      u0.x = f2bf_(acc[i][0] + bv2[0]); u0.y = f2bf_(acc[i][1] + bv2[1]);
      u0.z = f2bf_(acc[i][2] + bv2[2]); u0.w = f2bf_(acc[i][3] + bv2[3]);
      u1.x = f2bf_(acc[i][4] + bv2[4]); u1.y = f2bf_(acc[i][5] + bv2[5]);
      u1.z = f2bf_(acc[i][6] + bv2[6]); u1.w = f2bf_(acc[i][7] + bv2[7]);
      *reinterpret_cast<ushort4*>((uint16_t*)xw + row) = u0;
      *reinterpret_cast<ushort4*>((uint16_t*)xw + row + 4) = u1;
    }
  }
}

// ---------------------------------------------------------------------------
// One timestep. 256 blocks x 512 thr; block owns h-cols bid*4..+3 (16 gate
// rows), all 64 batch rows. W slice resident in LDS (staged coalesced from
// repacked Wt). h chunks (64n x 64k) double-buffered, XOR-swizzled units.
// 16-way K split (8 waves x kk2); lane tile 8n x 4jj for one gate. LDS
// 16-slice reduce, fused gate epilogue; c in global cbuf. PRE=1: adds
// precomputed xw[n][t][:]. PRE=0: x-phase accumulates x_t @ Wx (Wxt restaged
// mid-step), + bias.
// ---------------------------------------------------------------------------
template <int PRE, typename XT>
__global__ __launch_bounds__(512) void step_k(
    const float* __restrict__ Wt, const float* __restrict__ Wxt,
    const XT* __restrict__ xw, const float* __restrict__ bias,
    const float* __restrict__ xsrc,  // PRE=0: x + t*D (row stride T*D)
    const float* __restrict__ hsrc, long long hstr,
    float* __restrict__ cbuf, float* __restrict__ h_out, int t, int first) {
  extern __shared__ float lds[];
  float* const Wl = lds;            // 16384 f (64KB), swizzled units
  float* const red = lds + 16384;   // 16384 f (64KB)
  float4* const cbb = reinterpret_cast<float4*>(red);  // 2 x 1024 float4 overlay

  const int tid = threadIdx.x;
  const int bid = blockIdx.x;
  const int w = tid >> 6;
  const int lane = tid & 63;
  const int gci = lane & 3;          // gate
  const int ngi = (lane >> 2) & 7;   // n group (n = ngi + nn*8)
  const int kk2 = lane >> 5;
  const int col = (w << 1) | kk2;    // unit col within chunk (0..15)

  // xw prefetch / bias (latency hidden under whole step)
  float xwv[4] = {0.f, 0.f, 0.f, 0.f};
  if (tid < 256) {
    if (PRE) {
      const XT* xr = xw + ((size_t)(tid >> 2) * T_ + t) * FH + (bid << 2) + (tid & 3);
#pragma unroll
      for (int g = 0; g < 4; ++g) xwv[g] = ldxw_(xr + g * H_);
    } else {
#pragma unroll
      for (int g = 0; g < 4; ++g) xwv[g] = bias[g * H_ + (bid << 2) + (tid & 3)];
    }
  }

  // W stage: 8 float4/thread, coalesced from Wt, swizzled LDS units
  {
    const float4* src = reinterpret_cast<const float4*>(Wt) + (size_t)bid * 4096;
    float4 wreg[8];
#pragma unroll
    for (int rep = 0; rep < 8; ++rep) wreg[rep] = src[(rep << 9) | tid];
#pragma unroll
    for (int rep = 0; rep < 8; ++rep) {
      int idx = (rep << 9) | tid;
      int r = idx >> 8, u = idx & 255;
      *reinterpret_cast<float4*>(Wl + (r << 10) + ((u ^ (r & 7)) << 2)) = wreg[rep];
    }
  }

  // h chunk-0 stage: thread stages 2 units (32B)
  const int ub0 = tid << 1;
  const int sn = ub0 >> 4, sku = ub0 & 15;
  const int sw0 = sku ^ (sn & 7), sw1 = (sku + 1) ^ (sn & 7);
  {
    const float* gp = hsrc + (size_t)sn * hstr + (sku << 2);
    cbb[(sn << 4) + sw0] = *reinterpret_cast<const float4*>(gp);
    cbb[(sn << 4) + sw1] = *reinterpret_cast<const float4*>(gp + 4);
  }

  float acc[8][4];
#pragma unroll
  for (int nn = 0; nn < 8; ++nn)
#pragma unroll
    for (int g = 0; g < 4; ++g) acc[nn][g] = 0.f;
  __syncthreads();

  constexpr int NC = PRE ? 16 : 32;
  const int hswz = col ^ ngi;

  for (int c = 0; c < NC; ++c) {
    if (!PRE && c == 16) {  // restage W from Wxt (x-phase)
      const float4* src2 = reinterpret_cast<const float4*>(Wxt) + (size_t)bid * 4096;
      float4 wreg[8];
#pragma unroll
      for (int rep = 0; rep < 8; ++rep) wreg[rep] = src2[(rep << 9) | tid];
#pragma unroll
      for (int rep = 0; rep < 8; ++rep) {
        int idx = (rep << 9) | tid;
        int r = idx >> 8, u = idx & 255;
        *reinterpret_cast<float4*>(Wl + (r << 10) + ((u ^ (r & 7)) << 2)) = wreg[rep];
      }
      __syncthreads();
    }
    float4 s0, s1;
    const bool more = (c + 1 < NC);
    if (more) {  // issue next-chunk loads before compute (T14)
      const int cn = c + 1;
      const float* src; long long sstr;
      if (PRE || cn < 16) { src = hsrc; sstr = hstr; }
      else { src = xsrc; sstr = (long long)T_ * D_; }
      const float* gp = src + (size_t)sn * sstr + ((cn & 15) << 6) + (sku << 2);
      s0 = *reinterpret_cast<const float4*>(gp);
      s1 = *reinterpret_cast<const float4*>(gp + 4);
    }
    {
      const float4* cbr = cbb + ((c & 1) << 10);
      const int cu = ((c & 15) << 4) | col;
      float4 wv[4];
#pragma unroll
      for (int g = 0; g < 4; ++g) {
        const int r = (gci << 2) | g;
        wv[g] = *reinterpret_cast<const float4*>(Wl + (r << 10) + ((cu ^ (r & 7)) << 2));
      }
      float4 hv[8];
#pragma unroll
      for (int nn = 0; nn < 8; ++nn)
        hv[nn] = cbr[((ngi + (nn << 3)) << 4) + hswz];
#pragma unroll
      for (int nn = 0; nn < 8; ++nn)
#pragma unroll
        for (int g = 0; g < 4; ++g) {
          acc[nn][g] = fmaf(hv[nn].x, wv[g].x, acc[nn][g]);
          acc[nn][g] = fmaf(hv[nn].y, wv[g].y, acc[nn][g]);
          acc[nn][g] = fmaf(hv[nn].z, wv[g].z, acc[nn][g]);
          acc[nn][g] = fmaf(hv[nn].w, wv[g].w, acc[nn][g]);
        }
    }
    if (more) {
      float4* dst = cbb + (((c + 1) & 1) << 10);
      dst[(sn << 4) + sw0] = s0;
      dst[(sn << 4) + sw1] = s1;
    }
    __syncthreads();
  }

  // 16-slice K reduction
  const int slice = (w << 1) | kk2;
#pragma unroll
  for (int nn = 0; nn < 8; ++nn)
#pragma unroll
    for (int g = 0; g < 4; ++g)
      red[(slice << 10) + (((gci << 2) | g) << 6) + (ngi + (nn << 3))] = acc[nn][g];
  __syncthreads();
  {
    const int o2 = tid << 1;
    float r0 = 0.f, r1 = 0.f;
#pragma unroll
    for (int s = 0; s < 16; ++s) {
      r0 += red[(s << 10) + o2];
      r1 += red[(s << 10) + o2 + 1];
    }
    red[o2] = r0;       // in-place: per-thread-disjoint slots
    red[o2 + 1] = r1;
  }
  __syncthreads();

  if (tid < 256) {  // epilogue: n = tid>>2, jj = tid&3
    const int n = tid >> 2, jj = tid & 3;
    const int jg = (bid << 2) + jj;
    float a0 = red[(jj) * 64 + n] + xwv[0];
    float a1 = red[(4 + jj) * 64 + n] + xwv[1];
    float a2 = red[(8 + jj) * 64 + n] + xwv[2];
    float a3 = red[(12 + jj) * 64 + n] + xwv[3];
    float cp = first ? 0.0f : cbuf[n * H_ + jg];
    float iv = 1.f / (1.f + __expf(-a0));
    float fv = 1.f / (1.f + __expf(-a1));
    float ov = 1.f / (1.f + __expf(-a2));
    float gv = tanhf(a3);
    float cn = fmaf(fv, cp, iv * gv);
    cbuf[n * H_ + jg] = cn;
    h_out[(size_t)n * ((size_t)T_ * H_) + jg] = ov * tanhf(cn);
  }
}

// ---------------------------------------------------------------------------
// Tier-D fallback (tiny ws): round-1 fused per-step kernel (proven).
// ---------------------------------------------------------------------------
__global__ __launch_bounds__(256) void lstm_step_fb(
    const float* __restrict__ xt, const float* __restrict__ Wx,
    const float* __restrict__ Wh, const float* __restrict__ bias,
    const float* __restrict__ h_prev, long long hstride,
    float* __restrict__ cbuf, float* __restrict__ h_out, int first) {
  __shared__ float hS[32][128];
  __shared__ float wT[32][132];
  __shared__ float pre[32][34];
  const int tid = threadIdx.x;
  const int colblk = blockIdx.x & 127;
  const int nh = blockIdx.x >> 7;
  const int j0 = colblk << 3;
  const int n0 = nh << 5;
  const int ng = tid >> 4, cg2 = tid & 15;
  const int na = ng << 1, ca = cg2 << 1;

  float acc[2][2] = {{0.f, 0.f}, {0.f, 0.f}};

#pragma unroll
  for (int pr = 0; pr < 2; ++pr) {
    const float* src = (pr == 0) ? h_prev : xt;
    long long sstr = (pr == 0) ? hstride : (long long)T_ * D_;
    const float* W = (pr == 0) ? Wh : Wx;
    for (int k0 = 0; k0 < 1024; k0 += 128) {
      __syncthreads();
#pragma unroll
      for (int p = 0; p < 4; ++p) {
        int idx = tid + (p << 8);
        int r = idx >> 5, c4 = (idx & 31) << 2;
        *reinterpret_cast<float4*>(&hS[r][c4]) =
            *reinterpret_cast<const float4*>(src + (size_t)(n0 + r) * sstr + k0 + c4);
      }
#pragma unroll
      for (int p = 0; p < 4; ++p) {
        int idx = tid + (p << 8);
        int k = idx >> 3, sub = idx & 7;
        int g = sub >> 1, hf = (sub & 1) << 2;
        float4 v = *reinterpret_cast<const float4*>(
            W + (size_t)(k0 + k) * FH + g * H_ + j0 + hf);
        int cb = (g << 3) + hf;
        wT[cb][k] = v.x; wT[cb + 1][k] = v.y; wT[cb + 2][k] = v.z; wT[cb + 3][k] = v.w;
      }
      __syncthreads();
#pragma unroll
      for (int kk = 0; kk < 128; kk += 4) {
        float4 h0v = *reinterpret_cast<const float4*>(&hS[na][kk]);
        float4 h1v = *reinterpret_cast<const float4*>(&hS[na + 1][kk]);
        float4 w0 = *reinterpret_cast<const float4*>(&wT[ca][kk]);
        float4 w1 = *reinterpret_cast<const float4*>(&wT[ca + 1][kk]);
        acc[0][0] = fmaf(h0v.x, w0.x, acc[0][0]); acc[0][0] = fmaf(h0v.y, w0.y, acc[0][0]);
        acc[0][0] = fmaf(h0v.z, w0.z, acc[0][0]); acc[0][0] = fmaf(h0v.w, w0.w, acc[0][0]);
        acc[0][1] = fmaf(h0v.x, w1.x, acc[0][1]); acc[0][1] = fmaf(h0v.y, w1.y, acc[0][1]);
        acc[0][1] = fmaf(h0v.z, w1.z, acc[0][1]); acc[0][1] = fmaf(h0v.w, w1.w, acc[0][1]);
        acc[1][0] = fmaf(h1v.x, w0.x, acc[1][0]); acc[1][0] = fmaf(h1v.y, w0.y, acc[1][0]);
        acc[1][0] = fmaf(h1v.z, w0.z, acc[1][0]); acc[1][0] = fmaf(h1v.w, w0.w, acc[1][0]);
        acc[1][1] = fmaf(h1v.x, w1.x, acc[1][1]); acc[1][1] = fmaf(h1v.y, w1.y, acc[1][1]);
        acc[1][1] = fmaf(h1v.z, w1.z, acc[1][1]); acc[1][1] = fmaf(h1v.w, w1.w, acc[1][1]);
      }
    }
  }

  pre[na][ca] = acc[0][0];
  pre[na][ca + 1] = acc[0][1];
  pre[na + 1][ca] = acc[1][0];
  pre[na + 1][ca + 1] = acc[1][1];
  __syncthreads();

  const int nl = tid >> 3, jl = tid & 7;
  const int n = n0 + nl;
  const int jg = j0 + jl;
  float ai = pre[nl][jl] + bias[jg];
  float af = pre[nl][8 + jl] + bias[H_ + jg];
  float ao = pre[nl][16 + jl] + bias[2 * H_ + jg];
  float ag = pre[nl][24 + jl] + bias[3 * H_ + jg];
  float cp = first ? 0.0f : cbuf[n * H_ + jg];
  float iv = 1.f / (1.f + __expf(-ai));
  float fv = 1.f / (1.f + __expf(-af));
  float ov = 1.f / (1.f + __expf(-ao));
  float gv = tanhf(ag);
  float cn = fmaf(fv, cp, iv * gv);
  cbuf[n * H_ + jg] = cn;
  h_out[(size_t)n * ((size_t)T_ * H_) + jg] = ov * tanhf(cn);
}

// ---------------------------------------------------------------------------
extern "C" void kernel_launch(void* const* d_in, const int* in_sizes, int n_in,
                              void* d_out, int out_size, void* d_ws, size_t ws_size,
                              hipStream_t stream) {
  (void)in_sizes; (void)n_in; (void)out_size;
  const float* x  = (const float*)d_in[0];
  const float* h0 = (const float*)d_in[1];
  const float* Wx = (const float*)d_in[2];
  const float* Wh = (const float*)d_in[3];
  const float* b  = (const float*)d_in[4];
  float* out = (float*)d_out;

  const size_t CB = 1u << 20;                       // cbuf region (256KB used)
  const size_t WTB = 16u << 20;                     // repacked W bytes
  const size_t XW32 = (size_t)N_ * T_ * FH * 4;     // 512MB
  const size_t XW16 = XW32 / 2;
  char* p = (char*)d_ws;
  float* cbuf = (float*)p;
  float* Wt = (float*)(p + CB);
  const unsigned SH = 131072;  // 128 KiB dynamic LDS

  if (ws_size >= CB + WTB + XW32) {
    float* xwb = (float*)(p + CB + WTB);
    repack_k<<<dim3(4096), dim3(256), 0, stream>>>(Wh, Wt);
    gemm_xw_k<float><<<dim3(8192), dim3(256), 0, stream>>>(x, Wx, b, xwb);
    hipFuncSetAttribute((const void*)step_k<1, float>,
                        hipFuncAttributeMaxDynamicSharedMemorySize, (int)SH);
    for (int t = 0; t < T_; ++t) {
      const float* hp = (t == 0) ? h0 : out + (size_t)(t - 1) * H_;
      long long hstr = (t == 0) ? (long long)H_ : (long long)T_ * H_;
      step_k<1, float><<<dim3(256), dim3(512), SH, stream>>>(
          Wt, nullptr, xwb, nullptr, nullptr, hp, hstr, cbuf,
          out + (size_t)t * H_, t, t == 0);
    }
  } else if (ws_size >= CB + WTB + XW16) {
    uint16_t* xwb = (uint16_t*)(p + CB + WTB);
    repack_k<<<dim3(4096), dim3(256), 0, stream>>>(Wh, Wt);
    gemm_xw_k<uint16_t><<<dim3(8192), dim3(256), 0, stream>>>(x, Wx, b, xwb);
    hipFuncSetAttribute((const void*)step_k<1, uint16_t>,
                        hipFuncAttributeMaxDynamicSharedMemorySize, (int)SH);
    for (int t = 0; t < T_; ++t) {
      const float* hp = (t == 0) ? h0 : out + (size_t)(t - 1) * H_;
      long long hstr = (t == 0) ? (long long)H_ : (long long)T_ * H_;
      step_k<1, uint16_t><<<dim3(256), dim3(512), SH, stream>>>(
          Wt, nullptr, xwb, nullptr, nullptr, hp, hstr, cbuf,
          out + (size_t)t * H_, t, t == 0);
    }
  } else if (ws_size >= CB + 2 * WTB) {
    float* Wxt = (float*)(p + CB + WTB);
    repack_k<<<dim3(4096), dim3(256), 0, stream>>>(Wh, Wt);
    repack_k<<<dim3(4096), dim3(256), 0, stream>>>(Wx, Wxt);
    hipFuncSetAttribute((const void*)step_k<0, float>,
                        hipFuncAttributeMaxDynamicSharedMemorySize, (int)SH);
    for (int t = 0; t < T_; ++t) {
      const float* hp = (t == 0) ? h0 : out + (size_t)(t - 1) * H_;
      long long hstr = (t == 0) ? (long long)H_ : (long long)T_ * H_;
      step_k<0, float><<<dim3(256), dim3(512), SH, stream>>>(
          Wt, Wxt, (const float*)nullptr, b, x + (size_t)t * D_, hp, hstr, cbuf,
          out + (size_t)t * H_, t, t == 0);
    }
  } else {
    for (int t = 0; t < T_; ++t) {
      const float* hp = (t == 0) ? h0 : out + (size_t)(t - 1) * H_;
      long long hstr = (t == 0) ? (long long)H_ : (long long)T_ * H_;
      lstm_step_fb<<<dim3(256), dim3(256), 0, stream>>>(
          x + (size_t)t * D_, Wx, Wh, b, hp, hstr, cbuf,
          out + (size_t)t * H_, t == 0);
    }
  }
}

// Round 5
// 10335.831 us; speedup vs baseline: 3.0550x; 1.2153x over previous
//
#include <hip/hip_runtime.h>
#include <cstdint>
#include <cstddef>

#define N_ 64
#define T_ 512
#define D_ 1024
#define H_ 1024
#define FH 4096  // 4*H

typedef __attribute__((ext_vector_type(8))) short bf16x8;
typedef __attribute__((ext_vector_type(4))) float f32x4;

static __device__ __forceinline__ uint16_t f2bf_(float f) {
  union { float f; uint32_t u; } v; v.f = f;
  uint32_t u = v.u + 0x7FFFu + ((v.u >> 16) & 1u);
  return (uint16_t)(u >> 16);
}
static __device__ __forceinline__ float bf2f_(uint16_t s) {
  union { uint32_t u; float f; } v; v.u = ((uint32_t)s) << 16;
  return v.f;
}
static __device__ __forceinline__ float ldxw_(const float* p) { return *p; }
static __device__ __forceinline__ float ldxw_(const uint16_t* p) { return bf2f_(*p); }

// ---------------------------------------------------------------------------
// Pack W [1024][4096] into MFMA B-fragment order, split bf16 hi/lo.
// Fragment map (16x16x32): col c = lane&15 -> (gate g=c>>2, jj=c&3) of block
// bid; k = kc*32 + (lane>>4)*8 + e. Same map used for A loads => k-permutation
// cancels in the dot product. dst[( (bid*KCT + kcoff + kc)*64 + lane)*8 + e].
// Grid 2048 x 256 covers 256 bid x 32 kc x 64 lane.
// ---------------------------------------------------------------------------
template <int KCT>
__global__ __launch_bounds__(256) void pack_w_k(const float* __restrict__ W,
                                                ushort* __restrict__ hi,
                                                ushort* __restrict__ lo,
                                                int kcoff) {
  const int i = blockIdx.x * 256 + threadIdx.x;  // 524288
  const int lane = i & 63, kc = (i >> 6) & 31, bid = i >> 11;
  const int c = lane & 15;
  const int col = (c >> 2) * H_ + (bid << 2) + (c & 3);
  const int k0 = (kc << 5) + ((lane >> 4) << 3);
  const size_t o = ((size_t)(bid * KCT + kcoff + kc) * 64 + lane) * 8;
#pragma unroll
  for (int e = 0; e < 8; ++e) {
    float v = W[(size_t)(k0 + e) * FH + col];
    ushort h = f2bf_(v);
    hi[o + e] = h;
    lo[o + e] = f2bf_(v - bf2f_(h));
  }
}

// h0 [64][1024] f32 -> bf16 hi/lo, row-major. 64 blocks x 256 thr x 4 elems.
__global__ __launch_bounds__(256) void conv_h_k(const float* __restrict__ src,
                                                ushort* __restrict__ hi,
                                                ushort* __restrict__ lo) {
  const int i = blockIdx.x * 256 + threadIdx.x;  // 16384 float4s
  float4 v = reinterpret_cast<const float4*>(src)[i];
  ushort4 h, l;
  h.x = f2bf_(v.x); l.x = f2bf_(v.x - bf2f_(h.x));
  h.y = f2bf_(v.y); l.y = f2bf_(v.y - bf2f_(h.y));
  h.z = f2bf_(v.z); l.z = f2bf_(v.z - bf2f_(h.z));
  h.w = f2bf_(v.w); l.w = f2bf_(v.w - bf2f_(h.w));
  reinterpret_cast<ushort4*>(hi)[i] = h;
  reinterpret_cast<ushort4*>(lo)[i] = l;
}

// ---------------------------------------------------------------------------
// Phase 1: xW = x @ Wx + b. fp32 VALU GEMM (proven round-1/4).
// ---------------------------------------------------------------------------
template <typename ST>
__global__ __launch_bounds__(256) void gemm_xw_k(
    const float* __restrict__ x, const float* __restrict__ Wx,
    const float* __restrict__ bias, ST* __restrict__ xw) {
  __shared__ float As[16][128];
  __shared__ float Bs[16][128];
  const int tid = threadIdx.x;
  const int bn = blockIdx.x & 31;
  const int bm = blockIdx.x >> 5;
  const int m0 = bm << 7, n0 = bn << 7;
  const int ty = tid >> 4, tx = tid & 15;

  float acc[8][8];
#pragma unroll
  for (int i = 0; i < 8; ++i)
#pragma unroll
    for (int j = 0; j < 8; ++j) acc[i][j] = 0.0f;

  for (int k0 = 0; k0 < D_; k0 += 16) {
    __syncthreads();
#pragma unroll
    for (int p = 0; p < 2; ++p) {
      int idx = tid + (p << 8);
      int m = idx >> 2, kq = (idx & 3) << 2;
      float4 v = *reinterpret_cast<const float4*>(x + (size_t)(m0 + m) * D_ + k0 + kq);
      As[kq][m] = v.x; As[kq + 1][m] = v.y; As[kq + 2][m] = v.z; As[kq + 3][m] = v.w;
    }
#pragma unroll
    for (int p = 0; p < 2; ++p) {
      int idx = tid + (p << 8);
      int k = idx >> 5, c4 = (idx & 31) << 2;
      *reinterpret_cast<float4*>(&Bs[k][c4]) =
          *reinterpret_cast<const float4*>(Wx + (size_t)(k0 + k) * FH + n0 + c4);
    }
    __syncthreads();
#pragma unroll
    for (int k = 0; k < 16; ++k) {
      float4 a0 = *reinterpret_cast<const float4*>(&As[k][ty << 3]);
      float4 a1 = *reinterpret_cast<const float4*>(&As[k][(ty << 3) + 4]);
      float4 b0 = *reinterpret_cast<const float4*>(&Bs[k][tx << 3]);
      float4 b1 = *reinterpret_cast<const float4*>(&Bs[k][(tx << 3) + 4]);
      float av[8] = {a0.x, a0.y, a0.z, a0.w, a1.x, a1.y, a1.z, a1.w};
      float bv[8] = {b0.x, b0.y, b0.z, b0.w, b1.x, b1.y, b1.z, b1.w};
#pragma unroll
      for (int i = 0; i < 8; ++i)
#pragma unroll
        for (int j = 0; j < 8; ++j) acc[i][j] = fmaf(av[i], bv[j], acc[i][j]);
    }
  }

  float bv2[8];
#pragma unroll
  for (int j = 0; j < 8; ++j) bv2[j] = bias[n0 + (tx << 3) + j];

#pragma unroll
  for (int i = 0; i < 8; ++i) {
    size_t row = (size_t)(m0 + (ty << 3) + i) * FH + n0 + (tx << 3);
    if constexpr (sizeof(ST) == 4) {
      float4 o0, o1;
      o0.x = acc[i][0] + bv2[0]; o0.y = acc[i][1] + bv2[1];
      o0.z = acc[i][2] + bv2[2]; o0.w = acc[i][3] + bv2[3];
      o1.x = acc[i][4] + bv2[4]; o1.y = acc[i][5] + bv2[5];
      o1.z = acc[i][6] + bv2[6]; o1.w = acc[i][7] + bv2[7];
      *reinterpret_cast<float4*>((float*)xw + row) = o0;
      *reinterpret_cast<float4*>((float*)xw + row + 4) = o1;
    } else {
      ushort4 u0, u1;
      u0.x = f2bf_(acc[i][0] + bv2[0]); u0.y = f2bf_(acc[i][1] + bv2[1]);
      u0.z = f2bf_(acc[i][2] + bv2[2]); u0.w = f2bf_(acc[i][3] + bv2[3]);
      u1.x = f2bf_(acc[i][4] + bv2[4]); u1.y = f2bf_(acc[i][5] + bv2[5]);
      u1.z = f2bf_(acc[i][6] + bv2[6]); u1.w = f2bf_(acc[i][7] + bv2[7]);
      *reinterpret_cast<ushort4*>((uint16_t*)xw + row) = u0;
      *reinterpret_cast<ushort4*>((uint16_t*)xw + row + 4) = u1;
    }
  }
}

// ---------------------------------------------------------------------------
// MFMA step. 256 blocks x 512 thr (8 waves). Block = all 64 rows x 4 h-cols
// (16 gate cols c=g*4+jj). Split-bf16: D = Ah*Bh + Ah*Bl + Al*Bh.
// Waves: mt = w&3 (16-row M-tile), kh = w>>2 (K half). B slice (packed Wh
// hi/lo) staged to LDS. A frags loaded direct from hbuf ping-pong (bf16
// row-major). FUSED: kh=1 waves instead run x_t@Wx with on-the-fly f32->bf16
// hi/lo conversion (B rows 32..63 hold packed Wx). Epilogue via stride-17 LDS.
// ---------------------------------------------------------------------------
template <int FUSED, typename XT>
__global__ __launch_bounds__(512) void step_mfma_k(
    const ushort* __restrict__ Bpk_hi, const ushort* __restrict__ Bpk_lo,
    const XT* __restrict__ xw, const float* __restrict__ bias,
    const float* __restrict__ x,
    const ushort* __restrict__ hbi_hi, const ushort* __restrict__ hbi_lo,
    ushort* __restrict__ hbo_hi, ushort* __restrict__ hbo_lo,
    float* __restrict__ cbuf, float* __restrict__ out_t, int t, int first) {
  constexpr int KCT = FUSED ? 64 : 32;
  extern __shared__ char lds_raw[];
  ushort* const Bh = (ushort*)lds_raw;            // KCT*512 shorts
  ushort* const Bl = Bh + KCT * 512;
  float* const pre = (float*)(Bl + KCT * 512);    // [2][64][17]

  const int tid = threadIdx.x;
  const int bid = blockIdx.x;
  const int lane = tid & 63;
  const int w = tid >> 6;
  const int mt = w & 3, kh = w >> 2;

  float xwv[4] = {0.f, 0.f, 0.f, 0.f};
  const int en = tid >> 2, ejj = tid & 3;
  if (tid < 256) {
    if (FUSED) {
#pragma unroll
      for (int g = 0; g < 4; ++g) xwv[g] = bias[g * H_ + (bid << 2) + ejj];
    } else {
      const XT* xr = xw + ((size_t)en * T_ + t) * FH + (bid << 2) + ejj;
#pragma unroll
      for (int g = 0; g < 4; ++g) xwv[g] = ldxw_(xr + (size_t)g * H_);
    }
  }

  {  // stage B slices (coalesced float4, linear LDS)
    const float4* sh = reinterpret_cast<const float4*>(Bpk_hi + (size_t)bid * (KCT * 512));
    const float4* sl = reinterpret_cast<const float4*>(Bpk_lo + (size_t)bid * (KCT * 512));
    float4* dh = reinterpret_cast<float4*>(Bh);
    float4* dl = reinterpret_cast<float4*>(Bl);
#pragma unroll
    for (int i = 0; i < KCT / 8; ++i) {
      dh[tid + (i << 9)] = sh[tid + (i << 9)];
      dl[tid + (i << 9)] = sl[tid + (i << 9)];
    }
  }

  const int arow = (mt << 4) | (lane & 15);
  const int kg = lane >> 4;
  const bf16x8* Bfh = reinterpret_cast<const bf16x8*>(Bh) + lane;
  const bf16x8* Bfl = reinterpret_cast<const bf16x8*>(Bl) + lane;

  f32x4 acc = {0.f, 0.f, 0.f, 0.f};
  __syncthreads();

  if (!FUSED || kh == 0) {  // h part
    const char* Ah = (const char*)hbi_hi + arow * 2048 + (kg << 4);
    const char* Al = (const char*)hbi_lo + arow * 2048 + (kg << 4);
    const int k0 = FUSED ? 0 : (kh << 4);
    const int k1 = FUSED ? 32 : (k0 + 16);
#pragma unroll 8
    for (int kc = k0; kc < k1; ++kc) {
      bf16x8 ah = *reinterpret_cast<const bf16x8*>(Ah + (kc << 6));
      bf16x8 al = *reinterpret_cast<const bf16x8*>(Al + (kc << 6));
      bf16x8 bh = Bfh[kc << 6];
      bf16x8 bl = Bfl[kc << 6];
      acc = __builtin_amdgcn_mfma_f32_16x16x32_bf16(ah, bh, acc, 0, 0, 0);
      acc = __builtin_amdgcn_mfma_f32_16x16x32_bf16(ah, bl, acc, 0, 0, 0);
      acc = __builtin_amdgcn_mfma_f32_16x16x32_bf16(al, bh, acc, 0, 0, 0);
    }
  }
  if (FUSED && kh == 1) {  // x part, on-the-fly split
    const float* Ax = x + ((size_t)arow * T_ + t) * D_ + (kg << 3);
#pragma unroll 4
    for (int kcx = 0; kcx < 32; ++kcx) {
      float4 v0 = *reinterpret_cast<const float4*>(Ax + (kcx << 5));
      float4 v1 = *reinterpret_cast<const float4*>(Ax + (kcx << 5) + 4);
      float vf[8] = {v0.x, v0.y, v0.z, v0.w, v1.x, v1.y, v1.z, v1.w};
      bf16x8 ah, al;
#pragma unroll
      for (int e = 0; e < 8; ++e) {
        ushort h = f2bf_(vf[e]);
        ah[e] = (short)h;
        al[e] = (short)f2bf_(vf[e] - bf2f_(h));
      }
      const int kc = 32 + kcx;
      bf16x8 bh = Bfh[kc << 6];
      bf16x8 bl = Bfl[kc << 6];
      acc = __builtin_amdgcn_mfma_f32_16x16x32_bf16(ah, bh, acc, 0, 0, 0);
      acc = __builtin_amdgcn_mfma_f32_16x16x32_bf16(ah, bl, acc, 0, 0, 0);
      acc = __builtin_amdgcn_mfma_f32_16x16x32_bf16(al, bh, acc, 0, 0, 0);
    }
  }

  // D layout (m89-verified): col = lane&15, row = (lane>>4)*4 + r
  const int dc = lane & 15, dr = (lane >> 4) << 2;
#pragma unroll
  for (int r = 0; r < 4; ++r)
    pre[((kh << 6) | ((mt << 4) + dr + r)) * 17 + dc] = acc[r];
  __syncthreads();

  if (tid < 256) {  // epilogue: en = batch row, ejj = h-col within block
    const int jg = (bid << 2) + ejj;
    float a[4];
#pragma unroll
    for (int g = 0; g < 4; ++g)
      a[g] = pre[en * 17 + (g << 2) + ejj] + pre[(64 + en) * 17 + (g << 2) + ejj] +
             xwv[g];
    float cp = first ? 0.f : cbuf[en * H_ + jg];
    float iv = 1.f / (1.f + __expf(-a[0]));
    float fv = 1.f / (1.f + __expf(-a[1]));
    float ov = 1.f / (1.f + __expf(-a[2]));
    float gv = tanhf(a[3]);
    float cn = fmaf(fv, cp, iv * gv);
    cbuf[en * H_ + jg] = cn;
    float hn = ov * tanhf(cn);
    out_t[(size_t)en * ((size_t)T_ * H_) + jg] = hn;
    ushort hh = f2bf_(hn);
    hbo_hi[en * H_ + jg] = hh;
    hbo_lo[en * H_ + jg] = f2bf_(hn - bf2f_(hh));
  }
}

// ---------------------------------------------------------------------------
// Tier-D fallback (tiny ws): fused per-step VALU kernel (proven round-1).
// ---------------------------------------------------------------------------
__global__ __launch_bounds__(256) void lstm_step_fb(
    const float* __restrict__ xt, const float* __restrict__ Wx,
    const float* __restrict__ Wh, const float* __restrict__ bias,
    const float* __restrict__ h_prev, long long hstride,
    float* __restrict__ cbuf, float* __restrict__ h_out, int first) {
  __shared__ float hS[32][128];
  __shared__ float wT[32][132];
  __shared__ float pre[32][34];
  const int tid = threadIdx.x;
  const int colblk = blockIdx.x & 127;
  const int nh = blockIdx.x >> 7;
  const int j0 = colblk << 3;
  const int n0 = nh << 5;
  const int ng = tid >> 4, cg2 = tid & 15;
  const int na = ng << 1, ca = cg2 << 1;

  float acc[2][2] = {{0.f, 0.f}, {0.f, 0.f}};

#pragma unroll
  for (int pr = 0; pr < 2; ++pr) {
    const float* src = (pr == 0) ? h_prev : xt;
    long long sstr = (pr == 0) ? hstride : (long long)T_ * D_;
    const float* W = (pr == 0) ? Wh : Wx;
    for (int k0 = 0; k0 < 1024; k0 += 128) {
      __syncthreads();
#pragma unroll
      for (int p = 0; p < 4; ++p) {
        int idx = tid + (p << 8);
        int r = idx >> 5, c4 = (idx & 31) << 2;
        *reinterpret_cast<float4*>(&hS[r][c4]) =
            *reinterpret_cast<const float4*>(src + (size_t)(n0 + r) * sstr + k0 + c4);
      }
#pragma unroll
      for (int p = 0; p < 4; ++p) {
        int idx = tid + (p << 8);
        int k = idx >> 3, sub = idx & 7;
        int g = sub >> 1, hf = (sub & 1) << 2;
        float4 v = *reinterpret_cast<const float4*>(
            W + (size_t)(k0 + k) * FH + g * H_ + j0 + hf);
        int cb = (g << 3) + hf;
        wT[cb][k] = v.x; wT[cb + 1][k] = v.y; wT[cb + 2][k] = v.z; wT[cb + 3][k] = v.w;
      }
      __syncthreads();
#pragma unroll
      for (int kk = 0; kk < 128; kk += 4) {
        float4 h0v = *reinterpret_cast<const float4*>(&hS[na][kk]);
        float4 h1v = *reinterpret_cast<const float4*>(&hS[na + 1][kk]);
        float4 w0 = *reinterpret_cast<const float4*>(&wT[ca][kk]);
        float4 w1 = *reinterpret_cast<const float4*>(&wT[ca + 1][kk]);
        acc[0][0] = fmaf(h0v.x, w0.x, acc[0][0]); acc[0][0] = fmaf(h0v.y, w0.y, acc[0][0]);
        acc[0][0] = fmaf(h0v.z, w0.z, acc[0][0]); acc[0][0] = fmaf(h0v.w, w0.w, acc[0][0]);
        acc[0][1] = fmaf(h0v.x, w1.x, acc[0][1]); acc[0][1] = fmaf(h0v.y, w1.y, acc[0][1]);
        acc[0][1] = fmaf(h0v.z, w1.z, acc[0][1]); acc[0][1] = fmaf(h0v.w, w1.w, acc[0][1]);
        acc[1][0] = fmaf(h1v.x, w0.x, acc[1][0]); acc[1][0] = fmaf(h1v.y, w0.y, acc[1][0]);
        acc[1][0] = fmaf(h1v.z, w0.z, acc[1][0]); acc[1][0] = fmaf(h1v.w, w0.w, acc[1][0]);
        acc[1][1] = fmaf(h1v.x, w1.x, acc[1][1]); acc[1][1] = fmaf(h1v.y, w1.y, acc[1][1]);
        acc[1][1] = fmaf(h1v.z, w1.z, acc[1][1]); acc[1][1] = fmaf(h1v.w, w1.w, acc[1][1]);
      }
    }
  }

  pre[na][ca] = acc[0][0];
  pre[na][ca + 1] = acc[0][1];
  pre[na + 1][ca] = acc[1][0];
  pre[na + 1][ca + 1] = acc[1][1];
  __syncthreads();

  const int nl = tid >> 3, jl = tid & 7;
  const int n = n0 + nl;
  const int jg = j0 + jl;
  float ai = pre[nl][jl] + bias[jg];
  float af = pre[nl][8 + jl] + bias[H_ + jg];
  float ao = pre[nl][16 + jl] + bias[2 * H_ + jg];
  float ag = pre[nl][24 + jl] + bias[3 * H_ + jg];
  float cp = first ? 0.0f : cbuf[n * H_ + jg];
  float iv = 1.f / (1.f + __expf(-ai));
  float fv = 1.f / (1.f + __expf(-af));
  float ov = 1.f / (1.f + __expf(-ao));
  float gv = tanhf(ag);
  float cn = fmaf(fv, cp, iv * gv);
  cbuf[n * H_ + jg] = cn;
  h_out[(size_t)n * ((size_t)T_ * H_) + jg] = ov * tanhf(cn);
}

// ---------------------------------------------------------------------------
extern "C" void kernel_launch(void* const* d_in, const int* in_sizes, int n_in,
                              void* d_out, int out_size, void* d_ws, size_t ws_size,
                              hipStream_t stream) {
  (void)in_sizes; (void)n_in; (void)out_size;
  const float* x  = (const float*)d_in[0];
  const float* h0 = (const float*)d_in[1];
  const float* Wx = (const float*)d_in[2];
  const float* Wh = (const float*)d_in[3];
  const float* b  = (const float*)d_in[4];
  float* out = (float*)d_out;

  const size_t MB = 1u << 20;
  const size_t XW32 = (size_t)N_ * T_ * FH * 4;  // 512 MB
  const size_t XW16 = XW32 / 2;
  char* p = (char*)d_ws;
  float* cbuf = (float*)p;

  const unsigned SH_AB = 32 * 2048 + 8704;   // 74240 B
  const unsigned SH_C  = 64 * 2048 + 8704;   // 139776 B

  if (ws_size >= 18 * MB + XW32 || ws_size >= 18 * MB + XW16) {
    const bool f32xw = ws_size >= 18 * MB + XW32;
    ushort* wph = (ushort*)(p + 1 * MB);
    ushort* wpl = (ushort*)(p + 9 * MB);
    char* hb = p + 17 * MB;
    ushort* hbh[2] = {(ushort*)hb, (ushort*)(hb + 256 * 1024)};
    ushort* hbl[2] = {hbh[0] + 65536, hbh[1] + 65536};
    void* xwb = (void*)(p + 18 * MB);

    pack_w_k<32><<<dim3(2048), dim3(256), 0, stream>>>(Wh, wph, wpl, 0);
    conv_h_k<<<dim3(64), dim3(256), 0, stream>>>(h0, hbh[0], hbl[0]);
    if (f32xw) {
      gemm_xw_k<float><<<dim3(8192), dim3(256), 0, stream>>>(x, Wx, b, (float*)xwb);
      hipFuncSetAttribute((const void*)step_mfma_k<0, float>,
                          hipFuncAttributeMaxDynamicSharedMemorySize, (int)SH_AB);
      for (int t = 0; t < T_; ++t) {
        int i = t & 1, o = (t + 1) & 1;
        step_mfma_k<0, float><<<dim3(256), dim3(512), SH_AB, stream>>>(
            wph, wpl, (const float*)xwb, b, x, hbh[i], hbl[i], hbh[o], hbl[o],
            cbuf, out + (size_t)t * H_, t, t == 0);
      }
    } else {
      gemm_xw_k<uint16_t><<<dim3(8192), dim3(256), 0, stream>>>(x, Wx, b, (uint16_t*)xwb);
      hipFuncSetAttribute((const void*)step_mfma_k<0, uint16_t>,
                          hipFuncAttributeMaxDynamicSharedMemorySize, (int)SH_AB);
      for (int t = 0; t < T_; ++t) {
        int i = t & 1, o = (t + 1) & 1;
        step_mfma_k<0, uint16_t><<<dim3(256), dim3(512), SH_AB, stream>>>(
            wph, wpl, (const uint16_t*)xwb, b, x, hbh[i], hbl[i], hbh[o], hbl[o],
            cbuf, out + (size_t)t * H_, t, t == 0);
      }
    }
  } else if (ws_size >= 34 * MB) {
    // fused tier: packed Wh (kc 0..31) + Wx (kc 32..63); x converted in-kernel
    ushort* wph = (ushort*)(p + 1 * MB);
    ushort* wpl = (ushort*)(p + 17 * MB);
    char* hb = p + 33 * MB;
    ushort* hbh[2] = {(ushort*)hb, (ushort*)(hb + 256 * 1024)};
    ushort* hbl[2] = {hbh[0] + 65536, hbh[1] + 65536};

    pack_w_k<64><<<dim3(2048), dim3(256), 0, stream>>>(Wh, wph, wpl, 0);
    pack_w_k<64><<<dim3(2048), dim3(256), 0, stream>>>(Wx, wph, wpl, 32);
    conv_h_k<<<dim3(64), dim3(256), 0, stream>>>(h0, hbh[0], hbl[0]);
    hipFuncSetAttribute((const void*)step_mfma_k<1, float>,
                        hipFuncAttributeMaxDynamicSharedMemorySize, (int)SH_C);
    for (int t = 0; t < T_; ++t) {
      int i = t & 1, o = (t + 1) & 1;
      step_mfma_k<1, float><<<dim3(256), dim3(512), SH_C, stream>>>(
          wph, wpl, (const float*)nullptr, b, x, hbh[i], hbl[i], hbh[o], hbl[o],
          cbuf, out + (size_t)t * H_, t, t == 0);
    }
  } else {
    for (int t = 0; t < T_; ++t) {
      const float* hp = (t == 0) ? h0 : out + (size_t)(t - 1) * H_;
      long long hstr = (t == 0) ? (long long)H_ : (long long)T_ * H_;
      lstm_step_fb<<<dim3(256), dim3(256), 0, stream>>>(
          x + (size_t)t * D_, Wx, Wh, b, hp, hstr, cbuf,
          out + (size_t)t * H_, t == 0);
    }
  }
}